// Round 10
// baseline (174.176 us; speedup 1.0000x reference)
//
#include <hip/hip_runtime.h>
#include <stdint.h>

// Round 10: persistent-A qkv_gemm.
//  - 256 blocks x 512 thr, 1 block/CU (112KB LDS). Block owns 64 rows of Xb,
//    staged ONCE (64KB). Loops 12 (w,nt) tiles x 8 ksteps staging only B (16KB,
//    L2-hot broadcast: all blocks walk y in lockstep). 96 uniform ksteps/block
//    vs 8 -> prologue amortized, A-refetch (192MB) eliminated.
//  - V transposed inline via LDS (R9-verified pattern).
//  - convert_x + prep_weights fused into one launch.
//  score_pass / pv_pass verbatim R9 (proven).

typedef __attribute__((ext_vector_type(4))) float f32x4;
typedef __attribute__((ext_vector_type(8))) short short8;
typedef __attribute__((ext_vector_type(4))) short short4b;

__device__ __forceinline__ short f2bf(float f) {
    union { float f; uint32_t u; } v; v.f = f;
    uint32_t r = (v.u + 0x7FFFu + ((v.u >> 16) & 1u)) >> 16;   // RNE
    return (short)r;
}
__device__ __forceinline__ float bf2f(short s) {
    union { uint32_t u; float f; } v; v.u = ((uint32_t)(uint16_t)s) << 16; return v.f;
}
__device__ __forceinline__ float sigm(float x) { return 1.0f / (1.0f + __expf(-x)); }

__device__ __forceinline__ void gload_lds16(const void* g, void* l) {
    __builtin_amdgcn_global_load_lds(
        (const __attribute__((address_space(1))) void*)g,
        (__attribute__((address_space(3))) void*)l, 16, 0, 0);
}

#define VMBAR() asm volatile("s_waitcnt vmcnt(0)\n\ts_barrier" ::: "memory")

// ---------------------------------------------------------------- K0: convert X + prep weights (fused)
__global__ __launch_bounds__(256) void fused_prep(
    const float* __restrict__ X, const float* __restrict__ Wq,
    const float* __restrict__ Wv, const float* __restrict__ Wk,
    short* __restrict__ Xb, short* __restrict__ Wt)
{
    __shared__ float T[64 * 68];
    if (blockIdx.x < 4096) {
        size_t i = (size_t)blockIdx.x * 256 + threadIdx.x;     // 8 floats/thread
        const float4* src = reinterpret_cast<const float4*>(X) + i * 2;
        float4 a = src[0], b = src[1];
        short8 o;
        o[0] = f2bf(a.x); o[1] = f2bf(a.y); o[2] = f2bf(a.z); o[3] = f2bf(a.w);
        o[4] = f2bf(b.x); o[5] = f2bf(b.y); o[6] = f2bf(b.z); o[7] = f2bf(b.w);
        *reinterpret_cast<short8*>(Xb + i * 8) = o;
        return;
    }
    int bid = blockIdx.x - 4096;
    int w = bid >> 6;                 // 0..2
    int tile = bid & 63;
    int n0 = (tile & 7) * 64;
    int k0 = (tile >> 3) * 64;
    const float* W = (w == 0) ? Wq : (w == 1) ? Wv : Wk;
    int t = threadIdx.x;
    int tr = t >> 4, tc = t & 15;
    for (int rr = 0; rr < 4; ++rr) {
        int row = rr * 16 + tr;       // k-local
        float4 v = *reinterpret_cast<const float4*>(&W[(size_t)(k0 + row) * 512 + n0 + tc * 4]);
        T[row * 68 + tc * 4 + 0] = v.x;
        T[row * 68 + tc * 4 + 1] = v.y;
        T[row * 68 + tc * 4 + 2] = v.z;
        T[row * 68 + tc * 4 + 3] = v.w;
    }
    __syncthreads();
    for (int wr = 0; wr < 4; ++wr) {
        int nl = wr * 16 + tr;        // n-local
        short4b o;
        for (int i = 0; i < 4; ++i) o[i] = f2bf(T[(tc * 4 + i) * 68 + nl]);
        *reinterpret_cast<short4b*>(&Wt[((size_t)(w * 512 + n0 + nl)) * 512 + k0 + tc * 4]) = o;
    }
}

// ---------------------------------------------------------------- K2: QKV GEMM (persistent-A)
// 256 blocks x 512 thr. Block bid: rows m0=bid*64 (A 64x512 resident in LDS).
// y-loop 0..11: (w2=y>>2, nt=y&3) -> output 64x128 tile; B dbuf 2x16KB; 8 ksteps/y.
// Waves: 2M x 4N -> wave (wm=wv>>2 rows 32-band, wn=wv&3 cols 32-band), acc 2x2 frags.
__global__ __launch_bounds__(512) void qkv_gemm(
    const short* __restrict__ Xb,    // [16384][512] bf16
    const short* __restrict__ Wt,    // [3][512 n][512 k] bf16
    short* __restrict__ Qb, short* __restrict__ Kb, short* __restrict__ VtG)
{
    __shared__ short As[64 * 512];     // A resident: row r, col c at (c ^ ((r&7)<<3))
    __shared__ short Bs[2][128 * 64];  // B dbuf
    __shared__ short Ts[128 * 64];     // epilogue staging (16KB)

    int bid = blockIdx.x;
    int m0 = bid * 64;

    int tid = threadIdx.x;
    int wv = tid >> 6, lane = tid & 63;
    int wm = wv >> 2, wn = wv & 3;
    int ln = lane & 15, hi = lane >> 4;

    const short* Xsrc = Xb + (size_t)m0 * 512;

    // ---- stage A once: wave wv covers rows 8wv..8wv+7, one 1KB gload_lds per row
#pragma unroll
    for (int j = 0; j < 8; ++j) {
        int r = wv * 8 + j;
        const short* src = Xsrc + (size_t)r * 512 + ((lane * 8) ^ ((r & 7) << 3));
        gload_lds16(src, &As[r * 512]);
    }

    // B staging: 2 instrs/wave, rows w*16+j*8 .. +8 (1KB each)
    auto stageB = [&](const short* Bsrc, int ko, int buf) {
        int k0 = ko * 64;
#pragma unroll
        for (int j = 0; j < 2; ++j) {
            int r0 = wv * 16 + j * 8;
            int r = r0 + (lane >> 3);
            const short* src = Bsrc + (size_t)r * 512 + k0 + (((lane & 7) * 8) ^ ((r & 7) << 3));
            gload_lds16(src, &Bs[buf][r0 * 64]);
        }
    };

    stageB(Wt, 0, 0);                              // y=0 (w=0,nt=0), ko=0

    for (int y = 0; y < 12; ++y) {
        int w2 = y >> 2, nt = y & 3;
        const short* Bsrc = Wt + (size_t)w2 * 512 * 512 + (size_t)(nt * 128) * 512;

        f32x4 acc[2][2];
#pragma unroll
        for (int i = 0; i < 2; ++i)
#pragma unroll
            for (int j = 0; j < 2; ++j) acc[i][j] = {0.f, 0.f, 0.f, 0.f};

        for (int ko = 0; ko < 8; ++ko) {
            VMBAR();                               // B(ko) staged (and A on first pass)
            if (ko + 1 < 8) {
                stageB(Bsrc, ko + 1, (ko + 1) & 1);
            } else if (y + 1 < 12) {
                const short* Bn = Wt + (size_t)((y + 1) >> 2) * 512 * 512
                                     + (size_t)(((y + 1) & 3) * 128) * 512;
                stageB(Bn, 0, 0);                  // next y's first B -> buf0 (parity ok)
            }
            const short* Bc = Bs[ko & 1];
            int kbase = ko * 64;
#pragma unroll
            for (int kk = 0; kk < 2; ++kk) {
                int kof = kk * 32 + hi * 8;
                short8 af[2], bf[2];
#pragma unroll
                for (int mf = 0; mf < 2; ++mf) {
                    int r = wm * 32 + mf * 16 + ln;
                    af[mf] = *reinterpret_cast<const short8*>(
                        &As[r * 512 + ((kbase + kof) ^ ((r & 7) << 3))]);
                }
#pragma unroll
                for (int nf = 0; nf < 2; ++nf) {
                    int r = wn * 32 + nf * 16 + ln;
                    bf[nf] = *reinterpret_cast<const short8*>(
                        &Bc[r * 64 + (kof ^ ((r & 7) << 3))]);
                }
#pragma unroll
                for (int mf = 0; mf < 2; ++mf)
#pragma unroll
                    for (int nf = 0; nf < 2; ++nf)
                        acc[mf][nf] = __builtin_amdgcn_mfma_f32_16x16x32_bf16(af[mf], bf[nf], acc[mf][nf], 0, 0, 0);
            }
        }

        // ---- epilogue for tile y (Ts is dedicated -> no hazard with Bs)
        if (w2 < 2) {
            // row-major: Ts[64][128], coalesced stores
#pragma unroll
            for (int mf = 0; mf < 2; ++mf)
#pragma unroll
                for (int nf = 0; nf < 2; ++nf)
#pragma unroll
                    for (int j = 0; j < 4; ++j) {
                        int rl = wm * 32 + mf * 16 + hi * 4 + j;
                        int cl = wn * 32 + nf * 16 + ln;
                        Ts[rl * 128 + (cl ^ ((rl & 7) << 3))] = f2bf(sigm(acc[mf][nf][j]));
                    }
            __syncthreads();
            short* O = (w2 == 0) ? Qb : Kb;
            int r = tid >> 3, h = tid & 7;
#pragma unroll
            for (int i = 0; i < 2; ++i) {
                int c8 = h * 16 + i * 8;
                short8 v = *reinterpret_cast<const short8*>(&Ts[r * 128 + (c8 ^ ((r & 7) << 3))]);
                *reinterpret_cast<short8*>(&O[(size_t)(m0 + r) * 512 + nt * 128 + c8]) = v;
            }
        } else {
            // V: transposed in LDS: Ts[d=128][s=64], store Vt[b][d][s]
#pragma unroll
            for (int mf = 0; mf < 2; ++mf)
#pragma unroll
                for (int nf = 0; nf < 2; ++nf)
#pragma unroll
                    for (int j = 0; j < 4; ++j) {
                        int sl = wm * 32 + mf * 16 + hi * 4 + j;   // s-local 0..63
                        int dl = wn * 32 + nf * 16 + ln;           // d-local 0..127
                        Ts[dl * 64 + (sl ^ ((dl & 7) << 3))] = f2bf(sigm(acc[mf][nf][j]));
                    }
            __syncthreads();
            int bb = m0 >> 11;
            int s0 = m0 & 2047;
            int d = tid >> 2, h = tid & 3;
#pragma unroll
            for (int i = 0; i < 2; ++i) {
                int s8 = h * 16 + i * 8;
                short8 v = *reinterpret_cast<const short8*>(&Ts[d * 64 + (s8 ^ ((d & 7) << 3))]);
                *reinterpret_cast<short8*>(&VtG[((size_t)(bb * 512 + nt * 128 + d)) * 2048 + s0 + s8]) = v;
            }
        }
    }
}

// ---------------------------------------------------------------- PA: score pass (R9 verbatim)
__global__ __launch_bounds__(256, 2) void score_pass(
    const short* __restrict__ Qb, const short* __restrict__ Kb,
    short* __restrict__ Pc, float* __restrict__ Dpart)
{
    __shared__ short SMEM[2][16384];       // per buf: As | Bs; buf0 reused as Ts
    __shared__ float psum[2][128];

    const float scale = 0.044194173824159216f;   // 1/sqrt(512)

    int bid = blockIdx.x;
    int b = bid & 7;
    int idx = bid >> 3;
    int ti = 0;
    while ((ti + 1) * (ti + 2) / 2 <= idx) ++ti;
    int tj = idx - ti * (ti + 1) / 2;
    int m0 = ti * 128, n0 = tj * 128;

    int tid = threadIdx.x;
    int w = tid >> 6, lane = tid & 63;
    int wr = w >> 1, wc = w & 1;
    int ln = lane & 15, hi = lane >> 4;

    const short* Qsrc = Qb + (size_t)b * 2048 * 512 + (size_t)m0 * 512;
    const short* Ksrc = Kb + (size_t)b * 2048 * 512 + (size_t)n0 * 512;

    f32x4 acc[4][4];
#pragma unroll
    for (int i = 0; i < 4; ++i)
#pragma unroll
        for (int j = 0; j < 4; ++j) acc[i][j] = {0.f, 0.f, 0.f, 0.f};

    int srow = w * 8 + (lane >> 3);
    int ssc0 = (lane & 7) * 8;

#define SSTAGE(ko, buf)                                                            \
    {                                                                              \
        int _k0 = (ko) * 64;                                                       \
        _Pragma("unroll")                                                          \
        for (int _j = 0; _j < 4; ++_j) {                                           \
            int _r = srow + _j * 32;                                               \
            int _sc = ssc0 ^ ((_r & 7) << 3);                                      \
            gload_lds16(Qsrc + (size_t)_r * 512 + _k0 + _sc,                       \
                        &SMEM[buf][(w * 8 + _j * 32) * 64]);                       \
        }                                                                          \
        _Pragma("unroll")                                                          \
        for (int _j = 0; _j < 4; ++_j) {                                           \
            int _r = srow + _j * 32;                                               \
            int _sc = ssc0 ^ ((_r & 7) << 3);                                      \
            gload_lds16(Ksrc + (size_t)_r * 512 + _k0 + _sc,                       \
                        &SMEM[buf][8192 + (w * 8 + _j * 32) * 64]);                \
        }                                                                          \
    }

    SSTAGE(0, 0);
    for (int ko = 0; ko < 8; ++ko) {
        VMBAR();
        if (ko + 1 < 8) SSTAGE(ko + 1, (ko + 1) & 1);
        const short* As = SMEM[ko & 1];
        const short* Bs = SMEM[ko & 1] + 8192;
#pragma unroll
        for (int kk = 0; kk < 2; ++kk) {
            int kof = kk * 32 + hi * 8;
            int sw = (ln & 7) << 3;
            short8 af[4], bf[4];
#pragma unroll
            for (int mf = 0; mf < 4; ++mf)
                af[mf] = *reinterpret_cast<const short8*>(&As[(wr * 64 + mf * 16 + ln) * 64 + (kof ^ sw)]);
#pragma unroll
            for (int nf = 0; nf < 4; ++nf)
                bf[nf] = *reinterpret_cast<const short8*>(&Bs[(wc * 64 + nf * 16 + ln) * 64 + (kof ^ sw)]);
#pragma unroll
            for (int mf = 0; mf < 4; ++mf)
#pragma unroll
                for (int nf = 0; nf < 4; ++nf)
                    acc[mf][nf] = __builtin_amdgcn_mfma_f32_16x16x32_bf16(af[mf], bf[nf], acc[mf][nf], 0, 0, 0);
        }
    }
    __syncthreads();
#undef SSTAGE

    short* Ts = SMEM[0];
#pragma unroll
    for (int mf = 0; mf < 4; ++mf) {
        float rs[4] = {0.f, 0.f, 0.f, 0.f};
#pragma unroll
        for (int nf = 0; nf < 4; ++nf)
#pragma unroll
            for (int j = 0; j < 4; ++j) {
                int rl = wr * 64 + mf * 16 + hi * 4 + j;
                int cl = wc * 64 + nf * 16 + ln;
                int irow = m0 + rl, jcol = n0 + cl;
                float p = (jcol < irow) ? __expf(acc[mf][nf][j] * scale) : 0.f;
                short hs = f2bf(p);
                Ts[rl * 128 + (cl ^ ((rl & 7) << 3))] = hs;
                rs[j] += bf2f(hs);
            }
#pragma unroll
        for (int j = 0; j < 4; ++j) {
            float s = rs[j];
            s += __shfl_xor(s, 1);
            s += __shfl_xor(s, 2);
            s += __shfl_xor(s, 4);
            s += __shfl_xor(s, 8);
            if (ln == 0) psum[wc][wr * 64 + mf * 16 + hi * 4 + j] = s;
        }
    }
    __syncthreads();
    short* Ptile = Pc + (size_t)(b * 136 + idx) * 128 * 128;
    {
        int r = tid >> 1, h = tid & 1;
#pragma unroll
        for (int i = 0; i < 8; ++i) {
            int c8 = h * 64 + i * 8;
            short8 v = *reinterpret_cast<const short8*>(&Ts[r * 128 + (c8 ^ ((r & 7) << 3))]);
            *reinterpret_cast<short8*>(&Ptile[(size_t)r * 128 + c8]) = v;
        }
    }
    if (tid < 128)
        Dpart[((size_t)b * 16 + tj) * 2048 + m0 + tid] = psum[0][tid] + psum[1][tid];
}

// ---------------------------------------------------------------- PB: PV pass (R9 verbatim)
__global__ __launch_bounds__(256) void pv_pass(
    const short* __restrict__ Pc, const short* __restrict__ VtG,
    const float* __restrict__ Dpart, float* __restrict__ Out)
{
    __shared__ short SMEM[2][12288];   // per buf: As(P)[128][64] | Bs(V^T)[64][64]
    __shared__ float dnm[128];

    int bid = blockIdx.x;
    int b = bid & 7;
    int rr = bid >> 3;
    int grp = rr >> 5, off = rr & 31;
    int ti = (grp & 1) ? (15 - (off >> 1)) : (off >> 1);
    int colhalf = 2 * grp + (off & 1);
    int m0 = ti * 128, n0 = colhalf * 64;

    int tid = threadIdx.x;
    int w = tid >> 6, lane = tid & 63;
    int wr = w >> 1, wc = w & 1;
    int ln = lane & 15, hi = lane >> 4;

    if (tid < 128) {
        float s = 0.f;
        for (int tj = 0; tj <= ti; ++tj)
            s += Dpart[((size_t)b * 16 + tj) * 2048 + m0 + tid];
        int gi = m0 + tid;
        dnm[tid] = (gi == 0) ? 0.f : 1.0f / s;
    }

    const short* Ptiles = Pc + (size_t)(b * 136 + ti * (ti + 1) / 2) * 128 * 128;
    const short* Vsrc = VtG + (size_t)b * 512 * 2048 + (size_t)n0 * 2048;

    f32x4 acc[4][2];
#pragma unroll
    for (int i = 0; i < 4; ++i)
#pragma unroll
        for (int j = 0; j < 2; ++j) acc[i][j] = {0.f, 0.f, 0.f, 0.f};

    int srow = w * 8 + (lane >> 3);
    int ssc0 = (lane & 7) * 8;
    int nks = 2 * (ti + 1);

#define PSTAGE(ks, buf)                                                            \
    {                                                                              \
        int _tj = (ks) >> 1;                                                       \
        int _j0 = ((ks) & 1) * 64;                                                 \
        const short* _Pt = Ptiles + (size_t)_tj * 128 * 128;                       \
        _Pragma("unroll")                                                          \
        for (int _j = 0; _j < 4; ++_j) {                                           \
            int _r = srow + _j * 32;                                               \
            int _sc = ssc0 ^ ((_r & 7) << 3);                                      \
            gload_lds16(_Pt + (size_t)_r * 128 + _j0 + _sc,                        \
                        &SMEM[buf][(w * 8 + _j * 32) * 64]);                       \
        }                                                                          \
        _Pragma("unroll")                                                          \
        for (int _j = 0; _j < 2; ++_j) {                                           \
            int _r = srow + _j * 32;                                               \
            int _sc = ssc0 ^ ((_r & 7) << 3);                                      \
            gload_lds16(Vsrc + (size_t)_r * 2048 + _tj * 128 + _j0 + _sc,          \
                        &SMEM[buf][8192 + (w * 8 + _j * 32) * 64]);                \
        }                                                                          \
    }

    PSTAGE(0, 0);
    for (int ks = 0; ks < nks; ++ks) {
        VMBAR();
        if (ks + 1 < nks) PSTAGE(ks + 1, (ks + 1) & 1);
        const short* As = SMEM[ks & 1];
        const short* Bs = SMEM[ks & 1] + 8192;
#pragma unroll
        for (int kk = 0; kk < 2; ++kk) {
            int kof = kk * 32 + hi * 8;
            int sw = (ln & 7) << 3;
            short8 af[4], bf[2];
#pragma unroll
            for (int mf = 0; mf < 4; ++mf)
                af[mf] = *reinterpret_cast<const short8*>(&As[(wr * 64 + mf * 16 + ln) * 64 + (kof ^ sw)]);
#pragma unroll
            for (int nf = 0; nf < 2; ++nf)
                bf[nf] = *reinterpret_cast<const short8*>(&Bs[(wc * 32 + nf * 16 + ln) * 64 + (kof ^ sw)]);
#pragma unroll
            for (int mf = 0; mf < 4; ++mf)
#pragma unroll
                for (int nf = 0; nf < 2; ++nf)
                    acc[mf][nf] = __builtin_amdgcn_mfma_f32_16x16x32_bf16(af[mf], bf[nf], acc[mf][nf], 0, 0, 0);
        }
    }
    __syncthreads();
#undef PSTAGE

    float* Tf = reinterpret_cast<float*>(SMEM);      // [128][64] f32 = 32 KB
#pragma unroll
    for (int mf = 0; mf < 4; ++mf)
#pragma unroll
        for (int nf = 0; nf < 2; ++nf)
#pragma unroll
            for (int j = 0; j < 4; ++j) {
                int rl = wr * 64 + mf * 16 + hi * 4 + j;
                int cl = wc * 32 + nf * 16 + ln;
                Tf[rl * 64 + (cl ^ ((rl & 7) << 2))] = acc[mf][nf][j] * dnm[rl];
            }
    __syncthreads();
    {
        int r = tid >> 1, h = tid & 1;
        float* orow = Out + ((size_t)b * 2048 + m0 + r) * 512 + n0;
#pragma unroll
        for (int i = 0; i < 8; ++i) {
            int c4 = (h * 8 + i) * 4;
            float4 v = *reinterpret_cast<const float4*>(&Tf[r * 64 + (c4 ^ ((r & 7) << 2))]);
            *reinterpret_cast<float4*>(&orow[c4]) = v;
        }
    }
}

// ---------------------------------------------------------------- launch
extern "C" void kernel_launch(void* const* d_in, const int* in_sizes, int n_in,
                              void* d_out, int out_size, void* d_ws, size_t ws_size,
                              hipStream_t stream) {
    const float* X  = (const float*)d_in[0];
    const float* Wq = (const float*)d_in[1];
    const float* Wv = (const float*)d_in[2];
    const float* Wk = (const float*)d_in[3];
    float* Out = (float*)d_out;

    char* ws = (char*)d_ws;
    const size_t WT_BYTES  = (size_t)3 * 512 * 512 * 2;        // 1.5 MB
    const size_t MAT_BYTES = (size_t)16384 * 512 * 2;          // 16 MB each
    const size_t PC_BYTES  = (size_t)8 * 136 * 128 * 128 * 2;  // 34.9 MB
    short* Wt = (short*)ws;
    short* Qb = (short*)(ws + WT_BYTES);
    short* Kb = (short*)(ws + WT_BYTES + MAT_BYTES);
    short* Vt = (short*)(ws + WT_BYTES + 2 * MAT_BYTES);
    short* Pc = (short*)(ws + WT_BYTES + 3 * MAT_BYTES);
    short* Xb = Pc;                       // alias: Xb dead before score_pass writes Pc
    float* Dp = (float*)(ws + WT_BYTES + 3 * MAT_BYTES + PC_BYTES);

    fused_prep<<<4288, 256, 0, stream>>>(X, Wq, Wv, Wk, Xb, Wt);
    qkv_gemm<<<256, 512, 0, stream>>>(Xb, Wt, Qb, Kb, Vt);
    score_pass<<<1088, 256, 0, stream>>>(Qb, Kb, Pc, Dp);
    pv_pass<<<1024, 256, 0, stream>>>(Pc, Vt, Dp, Out);
}

// Round 11
// 153.186 us; speedup vs baseline: 1.1370x; 1.1370x over previous
//
#include <hip/hip_runtime.h>
#include <stdint.h>

// Round 11: qkv as fused 16384x1536x512 GEMM with 128x256 tiles (32 MFMA/kstep/wave,
// half the block-ksteps of R9) + XCD-chunked grid (A panels L2-resident per XCD,
// re-hit across the 2 y-slices each XCD owns per m-panel).
// Everything else: R9-exact (proven 140.5us): convert_x, prep_weights, score_pass, pv_pass.

typedef __attribute__((ext_vector_type(4))) float f32x4;
typedef __attribute__((ext_vector_type(8))) short short8;
typedef __attribute__((ext_vector_type(4))) short short4b;

__device__ __forceinline__ short f2bf(float f) {
    union { float f; uint32_t u; } v; v.f = f;
    uint32_t r = (v.u + 0x7FFFu + ((v.u >> 16) & 1u)) >> 16;   // RNE
    return (short)r;
}
__device__ __forceinline__ float bf2f(short s) {
    union { uint32_t u; float f; } v; v.u = ((uint32_t)(uint16_t)s) << 16; return v.f;
}
__device__ __forceinline__ float sigm(float x) { return 1.0f / (1.0f + __expf(-x)); }

__device__ __forceinline__ void gload_lds16(const void* g, void* l) {
    __builtin_amdgcn_global_load_lds(
        (const __attribute__((address_space(1))) void*)g,
        (__attribute__((address_space(3))) void*)l, 16, 0, 0);
}

#define VMBAR() asm volatile("s_waitcnt vmcnt(0)\n\ts_barrier" ::: "memory")

// ---------------------------------------------------------------- K0: X fp32 -> bf16
__global__ __launch_bounds__(256) void convert_x(
    const float* __restrict__ X, short* __restrict__ Xb)
{
    size_t i = (size_t)blockIdx.x * 256 + threadIdx.x;     // 8 floats/thread
    const float4* src = reinterpret_cast<const float4*>(X) + i * 2;
    float4 a = src[0], b = src[1];
    short8 o;
    o[0] = f2bf(a.x); o[1] = f2bf(a.y); o[2] = f2bf(a.z); o[3] = f2bf(a.w);
    o[4] = f2bf(b.x); o[5] = f2bf(b.y); o[6] = f2bf(b.z); o[7] = f2bf(b.w);
    *reinterpret_cast<short8*>(Xb + i * 8) = o;
}

// ---------------------------------------------------------------- K1: weights
__global__ __launch_bounds__(256) void prep_weights(
    const float* __restrict__ Wq, const float* __restrict__ Wv, const float* __restrict__ Wk,
    short* __restrict__ Wt)
{
    __shared__ float T[64 * 68];
    int bid = blockIdx.x;
    int w = bid >> 6;                 // 0..2
    int tile = bid & 63;
    int n0 = (tile & 7) * 64;
    int k0 = (tile >> 3) * 64;
    const float* W = (w == 0) ? Wq : (w == 1) ? Wv : Wk;
    int t = threadIdx.x;
    int tr = t >> 4, tc = t & 15;
    for (int rr = 0; rr < 4; ++rr) {
        int row = rr * 16 + tr;       // k-local
        float4 v = *reinterpret_cast<const float4*>(&W[(size_t)(k0 + row) * 512 + n0 + tc * 4]);
        T[row * 68 + tc * 4 + 0] = v.x;
        T[row * 68 + tc * 4 + 1] = v.y;
        T[row * 68 + tc * 4 + 2] = v.z;
        T[row * 68 + tc * 4 + 3] = v.w;
    }
    __syncthreads();
    for (int wr = 0; wr < 4; ++wr) {
        int nl = wr * 16 + tr;        // n-local
        short4b o;
        for (int i = 0; i < 4; ++i) o[i] = f2bf(T[(tc * 4 + i) * 68 + nl]);
        *reinterpret_cast<short4b*>(&Wt[((size_t)(w * 512 + n0 + nl)) * 512 + k0 + tc * 4]) = o;
    }
}

// ---------------------------------------------------------------- K2: QKV GEMM (128x256 tile)
// 768 blocks x 512 thr, 1 block/CU (96KB LDS). Fused B = Wt[1536][512].
// Grid: xcd=bid&7, r=bid>>3 in [0,96): mt = xcd*16 + r%16, y2 = r/16 in [0,6).
//   -> XCD's 16 A-panels (2MB) L2-resident, reused across its 2 y-slices per pass.
// Waves 2Mx4N: wave (wm=wv>>2, wn=wv&3) owns 64x64 -> 4x4 frags, 32 MFMA/kstep.
__global__ __launch_bounds__(512, 1) void qkv_gemm(
    const short* __restrict__ Xb,    // [16384][512] bf16
    const short* __restrict__ Wt,    // [1536][512] bf16 (fused Q|K|V weights, row-major n,k)
    short* __restrict__ Qb, short* __restrict__ Kb, short* __restrict__ VtG)
{
    __shared__ short SMEM[2][24576];   // per buf: As[128][64] (8192) | Bs[256][64] (16384)

    int bid = blockIdx.x;
    int xcd = bid & 7;
    int r5 = bid >> 3;                 // 0..95
    int mt = xcd * 16 + (r5 & 15);
    int y2 = r5 >> 4;                  // 0..5
    int m0 = mt * 128;
    int n2 = y2 * 256;                 // fused-N base (never straddles 512 boundary)

    int tid = threadIdx.x;
    int wv = tid >> 6, lane = tid & 63;
    int wm = wv >> 2, wn = wv & 3;
    int ln = lane & 15, hi = lane >> 4;

    f32x4 acc[4][4];
#pragma unroll
    for (int i = 0; i < 4; ++i)
#pragma unroll
        for (int j = 0; j < 4; ++j) acc[i][j] = {0.f, 0.f, 0.f, 0.f};

    const short* Asrc = Xb + (size_t)m0 * 512;
    const short* Bsrc = Wt + (size_t)n2 * 512;

    // staging: A 16KB (2 instr/wave), B 32KB (4 instr/wave); pre-swizzled source
#define STAGE(ko, buf)                                                             \
    {                                                                              \
        int _k0 = (ko) * 64;                                                       \
        _Pragma("unroll")                                                          \
        for (int _j = 0; _j < 2; ++_j) {                                           \
            int _r0 = wv * 16 + _j * 8;                                            \
            int _r = _r0 + (lane >> 3);                                            \
            int _sc = ((lane & 7) * 8) ^ ((_r & 7) << 3);                          \
            gload_lds16(Asrc + (size_t)_r * 512 + _k0 + _sc,                       \
                        &SMEM[buf][_r0 * 64]);                                     \
        }                                                                          \
        _Pragma("unroll")                                                          \
        for (int _j = 0; _j < 4; ++_j) {                                           \
            int _r0 = wv * 32 + _j * 8;                                            \
            int _r = _r0 + (lane >> 3);                                            \
            int _sc = ((lane & 7) * 8) ^ ((_r & 7) << 3);                          \
            gload_lds16(Bsrc + (size_t)_r * 512 + _k0 + _sc,                       \
                        &SMEM[buf][8192 + _r0 * 64]);                              \
        }                                                                          \
    }

    STAGE(0, 0);
    for (int ko = 0; ko < 8; ++ko) {
        VMBAR();                                     // buf[ko&1] staged
        if (ko + 1 < 8) STAGE(ko + 1, (ko + 1) & 1);
        const short* As = SMEM[ko & 1];
        const short* Bs = SMEM[ko & 1] + 8192;
#pragma unroll
        for (int kk = 0; kk < 2; ++kk) {
            int kof = kk * 32 + hi * 8;
            int sw = (ln & 7) << 3;
            short8 af[4], bf[4];
#pragma unroll
            for (int mf = 0; mf < 4; ++mf) {
                int rr = wm * 64 + mf * 16 + ln;
                af[mf] = *reinterpret_cast<const short8*>(&As[rr * 64 + (kof ^ sw)]);
            }
#pragma unroll
            for (int nf = 0; nf < 4; ++nf) {
                int rr = wn * 64 + nf * 16 + ln;
                bf[nf] = *reinterpret_cast<const short8*>(&Bs[rr * 64 + (kof ^ sw)]);
            }
#pragma unroll
            for (int mf = 0; mf < 4; ++mf)
#pragma unroll
                for (int nf = 0; nf < 4; ++nf)
                    acc[mf][nf] = __builtin_amdgcn_mfma_f32_16x16x32_bf16(af[mf], bf[nf], acc[mf][nf], 0, 0, 0);
        }
    }
    __syncthreads();                                 // all MFMA LDS reads done -> reuse SMEM
#undef STAGE

    int w2 = n2 >> 9;                                // 0:Q 1:K 2:V
    int nc = n2 & 511;                               // column base within the 512-wide output
    short* Ts = SMEM[0];                             // 64KB staging

    if (w2 < 2) {
        // Ts[128][256] row-major swizzled -> coalesced 16B stores
#pragma unroll
        for (int mf = 0; mf < 4; ++mf)
#pragma unroll
            for (int nf = 0; nf < 4; ++nf)
#pragma unroll
                for (int j = 0; j < 4; ++j) {
                    int rl = wm * 64 + mf * 16 + hi * 4 + j;
                    int cl = wn * 64 + nf * 16 + ln;
                    Ts[rl * 256 + (cl ^ ((rl & 7) << 3))] = f2bf(sigm(acc[mf][nf][j]));
                }
        __syncthreads();
        short* O = (w2 == 0) ? Qb : Kb;
        int rr = tid >> 2, h = tid & 3;              // 4 threads per 256-col row
#pragma unroll
        for (int i = 0; i < 8; ++i) {
            int c8 = h * 64 + i * 8;
            short8 v = *reinterpret_cast<const short8*>(&Ts[rr * 256 + (c8 ^ ((rr & 7) << 3))]);
            *reinterpret_cast<short8*>(&O[(size_t)(m0 + rr) * 512 + nc + c8]) = v;
        }
    } else {
        // V: transpose in LDS: Ts[256 d][128 s], store Vt[b][d][s]
#pragma unroll
        for (int mf = 0; mf < 4; ++mf)
#pragma unroll
            for (int nf = 0; nf < 4; ++nf)
#pragma unroll
                for (int j = 0; j < 4; ++j) {
                    int sl = wm * 64 + mf * 16 + hi * 4 + j;   // s-local 0..127
                    int dl = wn * 64 + nf * 16 + ln;           // d-local 0..255
                    Ts[dl * 128 + (sl ^ ((dl & 7) << 3))] = f2bf(sigm(acc[mf][nf][j]));
                }
        __syncthreads();
        int bb = m0 >> 11;
        int s0 = m0 & 2047;
        int d = tid >> 1, h = tid & 1;               // 2 threads per 128-col d-row
#pragma unroll
        for (int i = 0; i < 8; ++i) {
            int s8 = h * 64 + i * 8;
            short8 v = *reinterpret_cast<const short8*>(&Ts[d * 128 + (s8 ^ ((d & 7) << 3))]);
            *reinterpret_cast<short8*>(&VtG[((size_t)(bb * 512 + nc + d)) * 2048 + s0 + s8]) = v;
        }
    }
}

// ---------------------------------------------------------------- PA: score pass (R9 verbatim)
__global__ __launch_bounds__(256, 2) void score_pass(
    const short* __restrict__ Qb, const short* __restrict__ Kb,
    short* __restrict__ Pc, float* __restrict__ Dpart)
{
    __shared__ short SMEM[2][16384];       // per buf: As | Bs; buf0 reused as Ts
    __shared__ float psum[2][128];

    const float scale = 0.044194173824159216f;   // 1/sqrt(512)

    int bid = blockIdx.x;
    int b = bid & 7;
    int idx = bid >> 3;
    int ti = 0;
    while ((ti + 1) * (ti + 2) / 2 <= idx) ++ti;
    int tj = idx - ti * (ti + 1) / 2;
    int m0 = ti * 128, n0 = tj * 128;

    int tid = threadIdx.x;
    int w = tid >> 6, lane = tid & 63;
    int wr = w >> 1, wc = w & 1;
    int ln = lane & 15, hi = lane >> 4;

    const short* Qsrc = Qb + (size_t)b * 2048 * 512 + (size_t)m0 * 512;
    const short* Ksrc = Kb + (size_t)b * 2048 * 512 + (size_t)n0 * 512;

    f32x4 acc[4][4];
#pragma unroll
    for (int i = 0; i < 4; ++i)
#pragma unroll
        for (int j = 0; j < 4; ++j) acc[i][j] = {0.f, 0.f, 0.f, 0.f};

    int srow = w * 8 + (lane >> 3);
    int ssc0 = (lane & 7) * 8;

#define SSTAGE(ko, buf)                                                            \
    {                                                                              \
        int _k0 = (ko) * 64;                                                       \
        _Pragma("unroll")                                                          \
        for (int _j = 0; _j < 4; ++_j) {                                           \
            int _r = srow + _j * 32;                                               \
            int _sc = ssc0 ^ ((_r & 7) << 3);                                      \
            gload_lds16(Qsrc + (size_t)_r * 512 + _k0 + _sc,                       \
                        &SMEM[buf][(w * 8 + _j * 32) * 64]);                       \
        }                                                                          \
        _Pragma("unroll")                                                          \
        for (int _j = 0; _j < 4; ++_j) {                                           \
            int _r = srow + _j * 32;                                               \
            int _sc = ssc0 ^ ((_r & 7) << 3);                                      \
            gload_lds16(Ksrc + (size_t)_r * 512 + _k0 + _sc,                       \
                        &SMEM[buf][8192 + (w * 8 + _j * 32) * 64]);                \
        }                                                                          \
    }

    SSTAGE(0, 0);
    for (int ko = 0; ko < 8; ++ko) {
        VMBAR();
        if (ko + 1 < 8) SSTAGE(ko + 1, (ko + 1) & 1);
        const short* As = SMEM[ko & 1];
        const short* Bs = SMEM[ko & 1] + 8192;
#pragma unroll
        for (int kk = 0; kk < 2; ++kk) {
            int kof = kk * 32 + hi * 8;
            int sw = (ln & 7) << 3;
            short8 af[4], bf[4];
#pragma unroll
            for (int mf = 0; mf < 4; ++mf)
                af[mf] = *reinterpret_cast<const short8*>(&As[(wr * 64 + mf * 16 + ln) * 64 + (kof ^ sw)]);
#pragma unroll
            for (int nf = 0; nf < 4; ++nf)
                bf[nf] = *reinterpret_cast<const short8*>(&Bs[(wc * 64 + nf * 16 + ln) * 64 + (kof ^ sw)]);
#pragma unroll
            for (int mf = 0; mf < 4; ++mf)
#pragma unroll
                for (int nf = 0; nf < 4; ++nf)
                    acc[mf][nf] = __builtin_amdgcn_mfma_f32_16x16x32_bf16(af[mf], bf[nf], acc[mf][nf], 0, 0, 0);
        }
    }
    __syncthreads();
#undef SSTAGE

    short* Ts = SMEM[0];
#pragma unroll
    for (int mf = 0; mf < 4; ++mf) {
        float rs[4] = {0.f, 0.f, 0.f, 0.f};
#pragma unroll
        for (int nf = 0; nf < 4; ++nf)
#pragma unroll
            for (int j = 0; j < 4; ++j) {
                int rl = wr * 64 + mf * 16 + hi * 4 + j;
                int cl = wc * 64 + nf * 16 + ln;
                int irow = m0 + rl, jcol = n0 + cl;
                float p = (jcol < irow) ? __expf(acc[mf][nf][j] * scale) : 0.f;
                short hs = f2bf(p);
                Ts[rl * 128 + (cl ^ ((rl & 7) << 3))] = hs;
                rs[j] += bf2f(hs);
            }
#pragma unroll
        for (int j = 0; j < 4; ++j) {
            float s = rs[j];
            s += __shfl_xor(s, 1);
            s += __shfl_xor(s, 2);
            s += __shfl_xor(s, 4);
            s += __shfl_xor(s, 8);
            if (ln == 0) psum[wc][wr * 64 + mf * 16 + hi * 4 + j] = s;
        }
    }
    __syncthreads();
    short* Ptile = Pc + (size_t)(b * 136 + idx) * 128 * 128;
    {
        int r = tid >> 1, h = tid & 1;
#pragma unroll
        for (int i = 0; i < 8; ++i) {
            int c8 = h * 64 + i * 8;
            short8 v = *reinterpret_cast<const short8*>(&Ts[r * 128 + (c8 ^ ((r & 7) << 3))]);
            *reinterpret_cast<short8*>(&Ptile[(size_t)r * 128 + c8]) = v;
        }
    }
    if (tid < 128)
        Dpart[((size_t)b * 16 + tj) * 2048 + m0 + tid] = psum[0][tid] + psum[1][tid];
}

// ---------------------------------------------------------------- PB: PV pass (R9 verbatim)
__global__ __launch_bounds__(256) void pv_pass(
    const short* __restrict__ Pc, const short* __restrict__ VtG,
    const float* __restrict__ Dpart, float* __restrict__ Out)
{
    __shared__ short SMEM[2][12288];   // per buf: As(P)[128][64] | Bs(V^T)[64][64]
    __shared__ float dnm[128];

    int bid = blockIdx.x;
    int b = bid & 7;
    int rr = bid >> 3;
    int grp = rr >> 5, off = rr & 31;
    int ti = (grp & 1) ? (15 - (off >> 1)) : (off >> 1);
    int colhalf = 2 * grp + (off & 1);
    int m0 = ti * 128, n0 = colhalf * 64;

    int tid = threadIdx.x;
    int w = tid >> 6, lane = tid & 63;
    int wr = w >> 1, wc = w & 1;
    int ln = lane & 15, hi = lane >> 4;

    if (tid < 128) {
        float s = 0.f;
        for (int tj = 0; tj <= ti; ++tj)
            s += Dpart[((size_t)b * 16 + tj) * 2048 + m0 + tid];
        int gi = m0 + tid;
        dnm[tid] = (gi == 0) ? 0.f : 1.0f / s;
    }

    const short* Ptiles = Pc + (size_t)(b * 136 + ti * (ti + 1) / 2) * 128 * 128;
    const short* Vsrc = VtG + (size_t)b * 512 * 2048 + (size_t)n0 * 2048;

    f32x4 acc[4][2];
#pragma unroll
    for (int i = 0; i < 4; ++i)
#pragma unroll
        for (int j = 0; j < 2; ++j) acc[i][j] = {0.f, 0.f, 0.f, 0.f};

    int srow = w * 8 + (lane >> 3);
    int ssc0 = (lane & 7) * 8;
    int nks = 2 * (ti + 1);

#define PSTAGE(ks, buf)                                                            \
    {                                                                              \
        int _tj = (ks) >> 1;                                                       \
        int _j0 = ((ks) & 1) * 64;                                                 \
        const short* _Pt = Ptiles + (size_t)_tj * 128 * 128;                       \
        _Pragma("unroll")                                                          \
        for (int _j = 0; _j < 4; ++_j) {                                           \
            int _r = srow + _j * 32;                                               \
            int _sc = ssc0 ^ ((_r & 7) << 3);                                      \
            gload_lds16(_Pt + (size_t)_r * 128 + _j0 + _sc,                        \
                        &SMEM[buf][(w * 8 + _j * 32) * 64]);                       \
        }                                                                          \
        _Pragma("unroll")                                                          \
        for (int _j = 0; _j < 2; ++_j) {                                           \
            int _r = srow + _j * 32;                                               \
            int _sc = ssc0 ^ ((_r & 7) << 3);                                      \
            gload_lds16(Vsrc + (size_t)_r * 2048 + _tj * 128 + _j0 + _sc,          \
                        &SMEM[buf][8192 + (w * 8 + _j * 32) * 64]);                \
        }                                                                          \
    }

    PSTAGE(0, 0);
    for (int ks = 0; ks < nks; ++ks) {
        VMBAR();
        if (ks + 1 < nks) PSTAGE(ks + 1, (ks + 1) & 1);
        const short* As = SMEM[ks & 1];
        const short* Bs = SMEM[ks & 1] + 8192;
#pragma unroll
        for (int kk = 0; kk < 2; ++kk) {
            int kof = kk * 32 + hi * 8;
            int sw = (ln & 7) << 3;
            short8 af[4], bf[2];
#pragma unroll
            for (int mf = 0; mf < 4; ++mf)
                af[mf] = *reinterpret_cast<const short8*>(&As[(wr * 64 + mf * 16 + ln) * 64 + (kof ^ sw)]);
#pragma unroll
            for (int nf = 0; nf < 2; ++nf)
                bf[nf] = *reinterpret_cast<const short8*>(&Bs[(wc * 32 + nf * 16 + ln) * 64 + (kof ^ sw)]);
#pragma unroll
            for (int mf = 0; mf < 4; ++mf)
#pragma unroll
                for (int nf = 0; nf < 2; ++nf)
                    acc[mf][nf] = __builtin_amdgcn_mfma_f32_16x16x32_bf16(af[mf], bf[nf], acc[mf][nf], 0, 0, 0);
        }
    }
    __syncthreads();
#undef PSTAGE

    float* Tf = reinterpret_cast<float*>(SMEM);      // [128][64] f32 = 32 KB
#pragma unroll
    for (int mf = 0; mf < 4; ++mf)
#pragma unroll
        for (int nf = 0; nf < 2; ++nf)
#pragma unroll
            for (int j = 0; j < 4; ++j) {
                int rl = wr * 64 + mf * 16 + hi * 4 + j;
                int cl = wc * 32 + nf * 16 + ln;
                Tf[rl * 64 + (cl ^ ((rl & 7) << 2))] = acc[mf][nf][j] * dnm[rl];
            }
    __syncthreads();
    {
        int r = tid >> 1, h = tid & 1;
        float* orow = Out + ((size_t)b * 2048 + m0 + r) * 512 + n0;
#pragma unroll
        for (int i = 0; i < 8; ++i) {
            int c4 = (h * 8 + i) * 4;
            float4 v = *reinterpret_cast<const float4*>(&Tf[r * 64 + (c4 ^ ((r & 7) << 2))]);
            *reinterpret_cast<float4*>(&orow[c4]) = v;
        }
    }
}

// ---------------------------------------------------------------- launch
extern "C" void kernel_launch(void* const* d_in, const int* in_sizes, int n_in,
                              void* d_out, int out_size, void* d_ws, size_t ws_size,
                              hipStream_t stream) {
    const float* X  = (const float*)d_in[0];
    const float* Wq = (const float*)d_in[1];
    const float* Wv = (const float*)d_in[2];
    const float* Wk = (const float*)d_in[3];
    float* Out = (float*)d_out;

    char* ws = (char*)d_ws;
    const size_t WT_BYTES  = (size_t)3 * 512 * 512 * 2;        // 1.5 MB
    const size_t MAT_BYTES = (size_t)16384 * 512 * 2;          // 16 MB each
    const size_t PC_BYTES  = (size_t)8 * 136 * 128 * 128 * 2;  // 34.9 MB
    short* Wt = (short*)ws;
    short* Qb = (short*)(ws + WT_BYTES);
    short* Kb = (short*)(ws + WT_BYTES + MAT_BYTES);
    short* Vt = (short*)(ws + WT_BYTES + 2 * MAT_BYTES);
    short* Pc = (short*)(ws + WT_BYTES + 3 * MAT_BYTES);
    short* Xb = Pc;                       // alias: Xb dead before score_pass writes Pc
    float* Dp = (float*)(ws + WT_BYTES + 3 * MAT_BYTES + PC_BYTES);

    convert_x<<<4096, 256, 0, stream>>>(X, Xb);
    prep_weights<<<192, 256, 0, stream>>>(Wq, Wv, Wk, Wt);
    qkv_gemm<<<768, 512, 0, stream>>>(Xb, Wt, Qb, Kb, Vt);
    score_pass<<<1088, 256, 0, stream>>>(Qb, Kb, Pc, Dp);
    pv_pass<<<1024, 256, 0, stream>>>(Pc, Vt, Dp, Out);
}

// Round 12
// 152.139 us; speedup vs baseline: 1.1448x; 1.0069x over previous
//
#include <hip/hip_runtime.h>
#include <stdint.h>

// Round 12: qkv with TRIPLE-buffered counted-vmcnt pipeline (T3+T4, first real T4 use).
//  - Tile 128x256 (fused N=1536), BK=64, 8 waves, per-wave 64x64 (acc[4][4]).
//  - 3 LDS buffers x 48KB: consume KT t (buf t%3) while KT t+1 AND KT t+2 in flight.
//    vmcnt(6) at group end certifies KT t+1 (older 6 loads) while KT t+2's 6 fly ->
//    loads are NEVER drained to 0 mid-loop (the m218 counted-vmcnt lever).
//  - 2 MFMA-phases per KT (16 MFMA clusters, setprio, barrier pairs).
//  score_pass / pv_pass / convert_x / prep_weights: R9-exact (proven).

typedef __attribute__((ext_vector_type(4))) float f32x4;
typedef __attribute__((ext_vector_type(8))) short short8;
typedef __attribute__((ext_vector_type(4))) short short4b;

__device__ __forceinline__ short f2bf(float f) {
    union { float f; uint32_t u; } v; v.f = f;
    uint32_t r = (v.u + 0x7FFFu + ((v.u >> 16) & 1u)) >> 16;   // RNE
    return (short)r;
}
__device__ __forceinline__ float bf2f(short s) {
    union { uint32_t u; float f; } v; v.u = ((uint32_t)(uint16_t)s) << 16; return v.f;
}
__device__ __forceinline__ float sigm(float x) { return 1.0f / (1.0f + __expf(-x)); }

__device__ __forceinline__ void gload_lds16(const void* g, void* l) {
    __builtin_amdgcn_global_load_lds(
        (const __attribute__((address_space(1))) void*)g,
        (__attribute__((address_space(3))) void*)l, 16, 0, 0);
}

#define VMBAR() asm volatile("s_waitcnt vmcnt(0)\n\ts_barrier" ::: "memory")

// ---------------------------------------------------------------- K0: X fp32 -> bf16
__global__ __launch_bounds__(256) void convert_x(
    const float* __restrict__ X, short* __restrict__ Xb)
{
    size_t i = (size_t)blockIdx.x * 256 + threadIdx.x;     // 8 floats/thread
    const float4* src = reinterpret_cast<const float4*>(X) + i * 2;
    float4 a = src[0], b = src[1];
    short8 o;
    o[0] = f2bf(a.x); o[1] = f2bf(a.y); o[2] = f2bf(a.z); o[3] = f2bf(a.w);
    o[4] = f2bf(b.x); o[5] = f2bf(b.y); o[6] = f2bf(b.z); o[7] = f2bf(b.w);
    *reinterpret_cast<short8*>(Xb + i * 8) = o;
}

// ---------------------------------------------------------------- K1: weights
__global__ __launch_bounds__(256) void prep_weights(
    const float* __restrict__ Wq, const float* __restrict__ Wv, const float* __restrict__ Wk,
    short* __restrict__ Wt)
{
    __shared__ float T[64 * 68];
    int bid = blockIdx.x;
    int w = bid >> 6;                 // 0..2
    int tile = bid & 63;
    int n0 = (tile & 7) * 64;
    int k0 = (tile >> 3) * 64;
    const float* W = (w == 0) ? Wq : (w == 1) ? Wv : Wk;
    int t = threadIdx.x;
    int tr = t >> 4, tc = t & 15;
    for (int rr = 0; rr < 4; ++rr) {
        int row = rr * 16 + tr;       // k-local
        float4 v = *reinterpret_cast<const float4*>(&W[(size_t)(k0 + row) * 512 + n0 + tc * 4]);
        T[row * 68 + tc * 4 + 0] = v.x;
        T[row * 68 + tc * 4 + 1] = v.y;
        T[row * 68 + tc * 4 + 2] = v.z;
        T[row * 68 + tc * 4 + 3] = v.w;
    }
    __syncthreads();
    for (int wr = 0; wr < 4; ++wr) {
        int nl = wr * 16 + tr;        // n-local
        short4b o;
        for (int i = 0; i < 4; ++i) o[i] = f2bf(T[(tc * 4 + i) * 68 + nl]);
        *reinterpret_cast<short4b*>(&Wt[((size_t)(w * 512 + n0 + nl)) * 512 + k0 + tc * 4]) = o;
    }
}

// ---------------------------------------------------------------- K2: QKV GEMM (3-buf counted vmcnt)
// 768 blocks x 512 thr: nt2 = bid>>7 (0..5, fused-N 256-slice), mt = bid&127.
// Waves 2Mx4N: wave (wm=wv>>2, wn=wv&3) owns rows wm*64+, cols wn*64+ (acc[4][4]).
__global__ __launch_bounds__(512, 1) void qkv_gemm(
    const short* __restrict__ Xb,    // [16384][512] bf16
    const short* __restrict__ Wt,    // [1536][512] bf16 fused
    short* __restrict__ Qb, short* __restrict__ Kb, short* __restrict__ VtG)
{
    __shared__ short SMEM[3][24576];   // per buf: A[128][64] | B[256][64] at +8192  (144 KB)

    int bid = blockIdx.x;
    int nt2 = bid >> 7;                // 0..5
    int mt = bid & 127;
    int m0 = mt * 128;
    int n2 = nt2 * 256;

    int tid = threadIdx.x;
    int wv = tid >> 6, lane = tid & 63;
    int wm = wv >> 2, wn = wv & 3;
    int ln = lane & 15, hi = lane >> 4;

    const short* Asrc = Xb + (size_t)m0 * 512;
    const short* Bsrc = Wt + (size_t)n2 * 512;

    auto stageA = [&](int kt, int buf) {               // 2 loads: A[128][64]
#pragma unroll
        for (int j = 0; j < 2; ++j) {
            int r0 = wv * 16 + j * 8;
            int r = r0 + (lane >> 3);
            gload_lds16(Asrc + (size_t)r * 512 + kt * 64 + (((lane & 7) * 8) ^ ((r & 7) << 3)),
                        &SMEM[buf][r0 * 64]);
        }
    };
    auto stageBH = [&](int kt, int h, int buf) {       // 2 loads: B rows h*128..+128
#pragma unroll
        for (int j = 0; j < 2; ++j) {
            int r0 = h * 128 + wv * 16 + j * 8;
            int r = r0 + (lane >> 3);
            gload_lds16(Bsrc + (size_t)r * 512 + kt * 64 + (((lane & 7) * 8) ^ ((r & 7) << 3)),
                        &SMEM[buf][8192 + r0 * 64]);
        }
    };

    f32x4 acc[4][4];
#pragma unroll
    for (int i = 0; i < 4; ++i)
#pragma unroll
        for (int j = 0; j < 4; ++j) acc[i][j] = {0.f, 0.f, 0.f, 0.f};

    // prologue: KT0 -> buf0 (6 loads), KT1 -> buf1 (6 loads); certify KT0, KT1 flies
    stageA(0, 0); stageBH(0, 0, 0); stageBH(0, 1, 0);
    stageA(1, 1); stageBH(1, 0, 1); stageBH(1, 1, 1);
    asm volatile("s_waitcnt vmcnt(6)\n\ts_barrier" ::: "memory");

    int sw = (ln & 7) << 3;
    for (int t = 0; t < 8; ++t) {
        int bufc = t % 3;
        const short* As = SMEM[bufc];
        const short* Bsb = SMEM[bufc] + 8192;
        int b2 = (t + 2) % 3;
        bool st = (t + 2) < 8;

        // A fragments (shared by both phases)
        short8 af[2][4];
#pragma unroll
        for (int kk = 0; kk < 2; ++kk)
#pragma unroll
            for (int mf = 0; mf < 4; ++mf) {
                int r = wm * 64 + mf * 16 + ln;
                af[kk][mf] = *reinterpret_cast<const short8*>(&As[r * 64 + ((kk * 32 + hi * 8) ^ sw)]);
            }

        // ---- phase 1: nf 0,1
        short8 bfr[2][2];
#pragma unroll
        for (int kk = 0; kk < 2; ++kk)
#pragma unroll
            for (int nf = 0; nf < 2; ++nf) {
                int r = wn * 64 + nf * 16 + ln;
                bfr[kk][nf] = *reinterpret_cast<const short8*>(&Bsb[r * 64 + ((kk * 32 + hi * 8) ^ sw)]);
            }
        if (st) { stageA(t + 2, b2); stageBH(t + 2, 0, b2); }
        asm volatile("s_barrier" ::: "memory");
        __builtin_amdgcn_s_setprio(1);
#pragma unroll
        for (int kk = 0; kk < 2; ++kk)
#pragma unroll
            for (int mf = 0; mf < 4; ++mf)
#pragma unroll
                for (int nf = 0; nf < 2; ++nf)
                    acc[mf][nf] = __builtin_amdgcn_mfma_f32_16x16x32_bf16(af[kk][mf], bfr[kk][nf], acc[mf][nf], 0, 0, 0);
        __builtin_amdgcn_s_setprio(0);
        asm volatile("s_barrier" ::: "memory");

        // ---- phase 2: nf 2,3
#pragma unroll
        for (int kk = 0; kk < 2; ++kk)
#pragma unroll
            for (int nf = 0; nf < 2; ++nf) {
                int r = wn * 64 + (2 + nf) * 16 + ln;
                bfr[kk][nf] = *reinterpret_cast<const short8*>(&Bsb[r * 64 + ((kk * 32 + hi * 8) ^ sw)]);
            }
        if (st) stageBH(t + 2, 1, b2);
        // counted wait: older 6 (KT t+1) must land; newest 6 (KT t+2) keep flying
        if (t <= 5) asm volatile("s_waitcnt vmcnt(6)\n\ts_barrier" ::: "memory");
        else        asm volatile("s_waitcnt vmcnt(0)\n\ts_barrier" ::: "memory");
        __builtin_amdgcn_s_setprio(1);
#pragma unroll
        for (int kk = 0; kk < 2; ++kk)
#pragma unroll
            for (int mf = 0; mf < 4; ++mf)
#pragma unroll
                for (int nf = 0; nf < 2; ++nf)
                    acc[mf][2 + nf] = __builtin_amdgcn_mfma_f32_16x16x32_bf16(af[kk][mf], bfr[kk][nf], acc[mf][2 + nf], 0, 0, 0);
        __builtin_amdgcn_s_setprio(0);
        asm volatile("s_barrier" ::: "memory");
    }
    __syncthreads();                                   // SMEM reusable

    // ---- epilogue (R11-proven 128x256 pattern)
    int w2 = nt2 >> 1;                                 // 0:Q 1:K 2:V
    int nc = (nt2 & 1) * 256;
    short* Ts = &SMEM[0][0];                           // 64KB needed, 144KB available

    if (w2 < 2) {
#pragma unroll
        for (int mf = 0; mf < 4; ++mf)
#pragma unroll
            for (int nf = 0; nf < 4; ++nf)
#pragma unroll
                for (int j = 0; j < 4; ++j) {
                    int rl = wm * 64 + mf * 16 + hi * 4 + j;
                    int cl = wn * 64 + nf * 16 + ln;
                    Ts[rl * 256 + (cl ^ ((rl & 7) << 3))] = f2bf(sigm(acc[mf][nf][j]));
                }
        __syncthreads();
        short* O = (w2 == 0) ? Qb : Kb;
        int rr = tid >> 2, h = tid & 3;
#pragma unroll
        for (int i = 0; i < 8; ++i) {
            int c8 = h * 64 + i * 8;
            short8 v = *reinterpret_cast<const short8*>(&Ts[rr * 256 + (c8 ^ ((rr & 7) << 3))]);
            *reinterpret_cast<short8*>(&O[(size_t)(m0 + rr) * 512 + nc + c8]) = v;
        }
    } else {
        // V: transpose in LDS: Ts[256 d][128 s], store Vt[b][d][s]
#pragma unroll
        for (int mf = 0; mf < 4; ++mf)
#pragma unroll
            for (int nf = 0; nf < 4; ++nf)
#pragma unroll
                for (int j = 0; j < 4; ++j) {
                    int sl = wm * 64 + mf * 16 + hi * 4 + j;   // s-local 0..127
                    int dl = wn * 64 + nf * 16 + ln;           // d-local 0..255
                    Ts[dl * 128 + (sl ^ ((dl & 7) << 3))] = f2bf(sigm(acc[mf][nf][j]));
                }
        __syncthreads();
        int bb = m0 >> 11;
        int s0 = m0 & 2047;
        int d = tid >> 1, h = tid & 1;
#pragma unroll
        for (int i = 0; i < 8; ++i) {
            int s8 = h * 64 + i * 8;
            short8 v = *reinterpret_cast<const short8*>(&Ts[d * 128 + (s8 ^ ((d & 7) << 3))]);
            *reinterpret_cast<short8*>(&VtG[((size_t)(bb * 512 + nc + d)) * 2048 + s0 + s8]) = v;
        }
    }
}

// ---------------------------------------------------------------- PA: score pass (R9 verbatim)
__global__ __launch_bounds__(256, 2) void score_pass(
    const short* __restrict__ Qb, const short* __restrict__ Kb,
    short* __restrict__ Pc, float* __restrict__ Dpart)
{
    __shared__ short SMEM[2][16384];       // per buf: As | Bs; buf0 reused as Ts
    __shared__ float psum[2][128];

    const float scale = 0.044194173824159216f;   // 1/sqrt(512)

    int bid = blockIdx.x;
    int b = bid & 7;
    int idx = bid >> 3;
    int ti = 0;
    while ((ti + 1) * (ti + 2) / 2 <= idx) ++ti;
    int tj = idx - ti * (ti + 1) / 2;
    int m0 = ti * 128, n0 = tj * 128;

    int tid = threadIdx.x;
    int w = tid >> 6, lane = tid & 63;
    int wr = w >> 1, wc = w & 1;
    int ln = lane & 15, hi = lane >> 4;

    const short* Qsrc = Qb + (size_t)b * 2048 * 512 + (size_t)m0 * 512;
    const short* Ksrc = Kb + (size_t)b * 2048 * 512 + (size_t)n0 * 512;

    f32x4 acc[4][4];
#pragma unroll
    for (int i = 0; i < 4; ++i)
#pragma unroll
        for (int j = 0; j < 4; ++j) acc[i][j] = {0.f, 0.f, 0.f, 0.f};

    int srow = w * 8 + (lane >> 3);
    int ssc0 = (lane & 7) * 8;

#define SSTAGE(ko, buf)                                                            \
    {                                                                              \
        int _k0 = (ko) * 64;                                                       \
        _Pragma("unroll")                                                          \
        for (int _j = 0; _j < 4; ++_j) {                                           \
            int _r = srow + _j * 32;                                               \
            int _sc = ssc0 ^ ((_r & 7) << 3);                                      \
            gload_lds16(Qsrc + (size_t)_r * 512 + _k0 + _sc,                       \
                        &SMEM[buf][(w * 8 + _j * 32) * 64]);                       \
        }                                                                          \
        _Pragma("unroll")                                                          \
        for (int _j = 0; _j < 4; ++_j) {                                           \
            int _r = srow + _j * 32;                                               \
            int _sc = ssc0 ^ ((_r & 7) << 3);                                      \
            gload_lds16(Ksrc + (size_t)_r * 512 + _k0 + _sc,                       \
                        &SMEM[buf][8192 + (w * 8 + _j * 32) * 64]);                \
        }                                                                          \
    }

    SSTAGE(0, 0);
    for (int ko = 0; ko < 8; ++ko) {
        VMBAR();
        if (ko + 1 < 8) SSTAGE(ko + 1, (ko + 1) & 1);
        const short* As = SMEM[ko & 1];
        const short* Bs = SMEM[ko & 1] + 8192;
#pragma unroll
        for (int kk = 0; kk < 2; ++kk) {
            int kof = kk * 32 + hi * 8;
            int sw = (ln & 7) << 3;
            short8 af[4], bf[4];
#pragma unroll
            for (int mf = 0; mf < 4; ++mf)
                af[mf] = *reinterpret_cast<const short8*>(&As[(wr * 64 + mf * 16 + ln) * 64 + (kof ^ sw)]);
#pragma unroll
            for (int nf = 0; nf < 4; ++nf)
                bf[nf] = *reinterpret_cast<const short8*>(&Bs[(wc * 64 + nf * 16 + ln) * 64 + (kof ^ sw)]);
#pragma unroll
            for (int mf = 0; mf < 4; ++mf)
#pragma unroll
                for (int nf = 0; nf < 4; ++nf)
                    acc[mf][nf] = __builtin_amdgcn_mfma_f32_16x16x32_bf16(af[mf], bf[nf], acc[mf][nf], 0, 0, 0);
        }
    }
    __syncthreads();
#undef SSTAGE

    short* Ts = SMEM[0];
#pragma unroll
    for (int mf = 0; mf < 4; ++mf) {
        float rs[4] = {0.f, 0.f, 0.f, 0.f};
#pragma unroll
        for (int nf = 0; nf < 4; ++nf)
#pragma unroll
            for (int j = 0; j < 4; ++j) {
                int rl = wr * 64 + mf * 16 + hi * 4 + j;
                int cl = wc * 64 + nf * 16 + ln;
                int irow = m0 + rl, jcol = n0 + cl;
                float p = (jcol < irow) ? __expf(acc[mf][nf][j] * scale) : 0.f;
                short hs = f2bf(p);
                Ts[rl * 128 + (cl ^ ((rl & 7) << 3))] = hs;
                rs[j] += bf2f(hs);
            }
#pragma unroll
        for (int j = 0; j < 4; ++j) {
            float s = rs[j];
            s += __shfl_xor(s, 1);
            s += __shfl_xor(s, 2);
            s += __shfl_xor(s, 4);
            s += __shfl_xor(s, 8);
            if (ln == 0) psum[wc][wr * 64 + mf * 16 + hi * 4 + j] = s;
        }
    }
    __syncthreads();
    short* Ptile = Pc + (size_t)(b * 136 + idx) * 128 * 128;
    {
        int r = tid >> 1, h = tid & 1;
#pragma unroll
        for (int i = 0; i < 8; ++i) {
            int c8 = h * 64 + i * 8;
            short8 v = *reinterpret_cast<const short8*>(&Ts[r * 128 + (c8 ^ ((r & 7) << 3))]);
            *reinterpret_cast<short8*>(&Ptile[(size_t)r * 128 + c8]) = v;
        }
    }
    if (tid < 128)
        Dpart[((size_t)b * 16 + tj) * 2048 + m0 + tid] = psum[0][tid] + psum[1][tid];
}

// ---------------------------------------------------------------- PB: PV pass (R9 verbatim)
__global__ __launch_bounds__(256) void pv_pass(
    const short* __restrict__ Pc, const short* __restrict__ VtG,
    const float* __restrict__ Dpart, float* __restrict__ Out)
{
    __shared__ short SMEM[2][12288];   // per buf: As(P)[128][64] | Bs(V^T)[64][64]
    __shared__ float dnm[128];

    int bid = blockIdx.x;
    int b = bid & 7;
    int rr = bid >> 3;
    int grp = rr >> 5, off = rr & 31;
    int ti = (grp & 1) ? (15 - (off >> 1)) : (off >> 1);
    int colhalf = 2 * grp + (off & 1);
    int m0 = ti * 128, n0 = colhalf * 64;

    int tid = threadIdx.x;
    int w = tid >> 6, lane = tid & 63;
    int wr = w >> 1, wc = w & 1;
    int ln = lane & 15, hi = lane >> 4;

    if (tid < 128) {
        float s = 0.f;
        for (int tj = 0; tj <= ti; ++tj)
            s += Dpart[((size_t)b * 16 + tj) * 2048 + m0 + tid];
        int gi = m0 + tid;
        dnm[tid] = (gi == 0) ? 0.f : 1.0f / s;
    }

    const short* Ptiles = Pc + (size_t)(b * 136 + ti * (ti + 1) / 2) * 128 * 128;
    const short* Vsrc = VtG + (size_t)b * 512 * 2048 + (size_t)n0 * 2048;

    f32x4 acc[4][2];
#pragma unroll
    for (int i = 0; i < 4; ++i)
#pragma unroll
        for (int j = 0; j < 2; ++j) acc[i][j] = {0.f, 0.f, 0.f, 0.f};

    int srow = w * 8 + (lane >> 3);
    int ssc0 = (lane & 7) * 8;
    int nks = 2 * (ti + 1);

#define PSTAGE(ks, buf)                                                            \
    {                                                                              \
        int _tj = (ks) >> 1;                                                       \
        int _j0 = ((ks) & 1) * 64;                                                 \
        const short* _Pt = Ptiles + (size_t)_tj * 128 * 128;                       \
        _Pragma("unroll")                                                          \
        for (int _j = 0; _j < 4; ++_j) {                                           \
            int _r = srow + _j * 32;                                               \
            int _sc = ssc0 ^ ((_r & 7) << 3);                                      \
            gload_lds16(_Pt + (size_t)_r * 128 + _j0 + _sc,                        \
                        &SMEM[buf][(w * 8 + _j * 32) * 64]);                       \
        }                                                                          \
        _Pragma("unroll")                                                          \
        for (int _j = 0; _j < 2; ++_j) {                                           \
            int _r = srow + _j * 32;                                               \
            int _sc = ssc0 ^ ((_r & 7) << 3);                                      \
            gload_lds16(Vsrc + (size_t)_r * 2048 + _tj * 128 + _j0 + _sc,          \
                        &SMEM[buf][8192 + (w * 8 + _j * 32) * 64]);                \
        }                                                                          \
    }

    PSTAGE(0, 0);
    for (int ks = 0; ks < nks; ++ks) {
        VMBAR();
        if (ks + 1 < nks) PSTAGE(ks + 1, (ks + 1) & 1);
        const short* As = SMEM[ks & 1];
        const short* Bs = SMEM[ks & 1] + 8192;
#pragma unroll
        for (int kk = 0; kk < 2; ++kk) {
            int kof = kk * 32 + hi * 8;
            int sw = (ln & 7) << 3;
            short8 af[4], bf[2];
#pragma unroll
            for (int mf = 0; mf < 4; ++mf)
                af[mf] = *reinterpret_cast<const short8*>(&As[(wr * 64 + mf * 16 + ln) * 64 + (kof ^ sw)]);
#pragma unroll
            for (int nf = 0; nf < 2; ++nf)
                bf[nf] = *reinterpret_cast<const short8*>(&Bs[(wc * 32 + nf * 16 + ln) * 64 + (kof ^ sw)]);
#pragma unroll
            for (int mf = 0; mf < 4; ++mf)
#pragma unroll
                for (int nf = 0; nf < 2; ++nf)
                    acc[mf][nf] = __builtin_amdgcn_mfma_f32_16x16x32_bf16(af[mf], bf[nf], acc[mf][nf], 0, 0, 0);
        }
    }
    __syncthreads();
#undef PSTAGE

    float* Tf = reinterpret_cast<float*>(SMEM);      // [128][64] f32 = 32 KB
#pragma unroll
    for (int mf = 0; mf < 4; ++mf)
#pragma unroll
        for (int nf = 0; nf < 2; ++nf)
#pragma unroll
            for (int j = 0; j < 4; ++j) {
                int rl = wr * 64 + mf * 16 + hi * 4 + j;
                int cl = wc * 32 + nf * 16 + ln;
                Tf[rl * 64 + (cl ^ ((rl & 7) << 2))] = acc[mf][nf][j] * dnm[rl];
            }
    __syncthreads();
    {
        int r = tid >> 1, h = tid & 1;
        float* orow = Out + ((size_t)b * 2048 + m0 + r) * 512 + n0;
#pragma unroll
        for (int i = 0; i < 8; ++i) {
            int c4 = (h * 8 + i) * 4;
            float4 v = *reinterpret_cast<const float4*>(&Tf[r * 64 + (c4 ^ ((r & 7) << 2))]);
            *reinterpret_cast<float4*>(&orow[c4]) = v;
        }
    }
}

// ---------------------------------------------------------------- launch
extern "C" void kernel_launch(void* const* d_in, const int* in_sizes, int n_in,
                              void* d_out, int out_size, void* d_ws, size_t ws_size,
                              hipStream_t stream) {
    const float* X  = (const float*)d_in[0];
    const float* Wq = (const float*)d_in[1];
    const float* Wv = (const float*)d_in[2];
    const float* Wk = (const float*)d_in[3];
    float* Out = (float*)d_out;

    char* ws = (char*)d_ws;
    const size_t WT_BYTES  = (size_t)3 * 512 * 512 * 2;        // 1.5 MB
    const size_t MAT_BYTES = (size_t)16384 * 512 * 2;          // 16 MB each
    const size_t PC_BYTES  = (size_t)8 * 136 * 128 * 128 * 2;  // 34.9 MB
    short* Wt = (short*)ws;
    short* Qb = (short*)(ws + WT_BYTES);
    short* Kb = (short*)(ws + WT_BYTES + MAT_BYTES);
    short* Vt = (short*)(ws + WT_BYTES + 2 * MAT_BYTES);
    short* Pc = (short*)(ws + WT_BYTES + 3 * MAT_BYTES);
    short* Xb = Pc;                       // alias: Xb dead before score_pass writes Pc
    float* Dp = (float*)(ws + WT_BYTES + 3 * MAT_BYTES + PC_BYTES);

    convert_x<<<4096, 256, 0, stream>>>(X, Xb);
    prep_weights<<<192, 256, 0, stream>>>(Wq, Wv, Wk, Wt);
    qkv_gemm<<<768, 512, 0, stream>>>(Xb, Wt, Qb, Kb, Vt);
    score_pass<<<1088, 256, 0, stream>>>(Qb, Kb, Pc, Dp);
    pv_pass<<<1024, 256, 0, stream>>>(Pc, Vt, Dp, Out);
}